// Round 5
// baseline (40.194 us; speedup 1.0000x reference)
//
#include <hip/hip_runtime.h>
#include <math.h>

#define G 24
#define NPTS (G * G)      // 576
#define ROWS (NPTS + 1)   // 577
#define HD 64
#define BH (8 * 12)       // 96
#define EPSF 0.1f
#define COEFF 576.0f
#define BSHIFT 6.3543700408f  // log(575)
#define PAIRS 289             // ceil(577/2) row-pairs per image
#define WPB 4                 // waves per block
// total waves = 96*289 = 27744 = 6936 blocks * 4 — exact, no guard needed

typedef float f32x4 __attribute__((ext_vector_type(4)));

__global__ __launch_bounds__(256) void gaussian_augment_kernel(
    const float* __restrict__ q,
    const float* __restrict__ Wv,
    const float* __restrict__ bv,
    const float* __restrict__ Wa,
    const float* __restrict__ ba,
    float* __restrict__ out)
{
    const int tid  = threadIdx.x;
    const int lane = tid & 63;
    const int wv   = tid >> 6;

    // layout per wave: [0..24) ex0 rowA | [24..48) ex1 rowA | [48..72) ex0 rowB | [72..96) ex1 rowB
    __shared__ float s_tab[WPB][96];

    const int gw = blockIdx.x * WPB + wv;   // global wave id
    const int bh = gw / PAIRS;              // magic-mul
    const int p  = gw - bh * PAIRS;
    const int rA = 2 * p;
    const bool twoRows = (rA + 1) < ROWS;

    // ---- dot products for both rows, jointly (6 accumulators, 6 butterfly steps) ----
    const float* qbase = q + ((size_t)bh * ROWS + rA) * HD;
    const float qv0 = qbase[lane];
    const float qv1 = twoRows ? qbase[HD + lane] : 0.0f;
    const float w0 = Wv[2 * lane + 0];
    const float w1 = Wv[2 * lane + 1];
    const float wa = Wa[lane];

    float a0 = qv0 * w0, a1 = qv0 * w1, a2 = qv0 * wa;
    float b0 = qv1 * w0, b1 = qv1 * w1, b2 = qv1 * wa;
    #pragma unroll
    for (int off = 32; off >= 1; off >>= 1) {
        a0 += __shfl_xor(a0, off);
        a1 += __shfl_xor(a1, off);
        a2 += __shfl_xor(a2, off);
        b0 += __shfl_xor(b0, off);
        b1 += __shfl_xor(b1, off);
        b2 += __shfl_xor(b2, off);
    }
    // all lanes now hold all 6 sums (wave-uniform)

    // ---- per-row params, computed wave-uniformly (same cost as 1 lane) ----
    const float bv0 = bv[0], bv1 = bv[1], ba0 = ba[0];

    const float varA0 = COEFF / (1.0f + expf(-(a0 + bv0 - BSHIFT)));
    const float varA1 = COEFF / (1.0f + expf(-(a1 + bv1 - BSHIFT)));
    const float invA0 = 1.0f / (varA0 + EPSF);
    const float invA1 = 1.0f / (varA1 + EPSF);
    const float xaA   = a2 + ba0;
    float alphaA = fmaxf(xaA, 0.0f) + log1pf(expf(-fabsf(xaA)));
    if (rA == 0) alphaA = 0.0f;   // prefix (pad) row -> all zeros

    const float varB0 = COEFF / (1.0f + expf(-(b0 + bv0 - BSHIFT)));
    const float varB1 = COEFF / (1.0f + expf(-(b1 + bv1 - BSHIFT)));
    const float invB0 = 1.0f / (varB0 + EPSF);
    const float invB1 = 1.0f / (varB1 + EPSF);
    const float xaB   = b2 + ba0;
    float alphaB = fmaxf(xaB, 0.0f) + log1pf(expf(-fabsf(xaB)));
    if (!twoRows) alphaB = 0.0f;  // rowB never the pad row (index odd)

    // ---- grid coords of the two rows ----
    const int nA = (rA > 0) ? rA - 1 : 0;
    const int iA = nA / G, jA = nA - (nA / G) * G;
    const int rB = rA + 1;
    const int nB = rB - 1;                 // rB >= 1 always
    const int iB = nB / G, jB = nB - (nB / G) * G;

    // ---- 96 absolute-indexed table entries (lanes 0..47, both rows) ----
    if (lane < 48) {
        const bool isJ = lane >= 24;
        const int  k   = isJ ? lane - 24 : lane;      // im or jm = k
        const float tA = (float)((isJ ? jA : iA) - k);
        const float sA = isJ ? invA1 : invA0;
        const float mA = isJ ? 1.0f : alphaA;
        s_tab[wv][lane] = mA * expf(-0.5f * tA * tA * sA);

        const float tB = (float)((isJ ? jB : iB) - k);
        const float sB = isJ ? invB1 : invB0;
        const float mB = isJ ? 1.0f : alphaB;
        s_tab[wv][48 + lane] = mB * expf(-0.5f * tB * tB * sB);
    }
    // DS ops within a wave are in-order: no barrier needed (same wave produces & consumes)

    // ---- stream the contiguous (up to) 2-row span, aligned nt dwordx4 ----
    const size_t base = ((size_t)bh * ROWS + rA) * ROWS;
    const int span  = twoRows ? 2 * ROWS : ROWS;
    const size_t S0 = base & ~(size_t)3;
    const int   off = (int)(base - S0);       // 0..3
    const int   nch = (span + off + 3) >> 2;
    const float* tw = s_tab[wv];

    for (int idx = lane; idx < nch; idx += 64) {
        const int e0 = 4 * idx - off;
        float v[4];
        #pragma unroll
        for (int t = 0; t < 4; ++t) {
            const int e = e0 + t;
            float val = 0.0f;
            if (e >= 0 && e < span) {
                const int rsel = (e >= ROWS) ? 48 : 0;   // row B half of table
                const int c    = (e >= ROWS) ? e - ROWS : e;
                if (c > 0) {
                    const unsigned m = (unsigned)(c - 1);
                    const int im = (int)(m / 24u);        // magic-mul
                    const int jm = (int)m - im * 24;
                    val = tw[rsel + im] * tw[rsel + 24 + jm];
                }
            }
            v[t] = val;
        }
        const size_t g0 = S0 + (size_t)4 * idx;
        if (e0 >= 0 && e0 + 4 <= span) {
            f32x4 pk = { v[0], v[1], v[2], v[3] };
            __builtin_nontemporal_store(pk, (f32x4*)(out + g0));
        } else {
            #pragma unroll
            for (int t = 0; t < 4; ++t) {
                const int e = e0 + t;
                if (e >= 0 && e < span) out[g0 + t] = v[t];
            }
        }
    }
}

extern "C" void kernel_launch(void* const* d_in, const int* in_sizes, int n_in,
                              void* d_out, int out_size, void* d_ws, size_t ws_size,
                              hipStream_t stream) {
    const float* q  = (const float*)d_in[0];
    const float* Wv = (const float*)d_in[1];
    const float* bv = (const float*)d_in[2];
    const float* Wa = (const float*)d_in[3];
    const float* ba = (const float*)d_in[4];
    float* out = (float*)d_out;

    const int grid = (BH * PAIRS) / WPB;  // 6936 blocks, 4 independent waves each
    gaussian_augment_kernel<<<grid, 256, 0, stream>>>(q, Wv, bv, Wa, ba, out);
}